// Round 4
// baseline (871.643 us; speedup 1.0000x reference)
//
#include <hip/hip_runtime.h>
#include <hip/hip_bf16.h>
#include <math.h>

#define NH 8
#define HS 64
#define VOCAB 16384
#define QPH 2048                         // queries per head = b(4) * t(512)
// fold 1/sqrt(512) * log2(e) into Q so the epilogue is p = exp2(score)
#define QSCALE (0.04419417382415922f * 1.4426950408889634f)

typedef __attribute__((ext_vector_type(8))) short bf16x8;
typedef __attribute__((ext_vector_type(4))) float f32x4;

static __device__ __forceinline__ unsigned short f2bf(float f) {
    __hip_bfloat16 h = __float2bfloat16(f);
    unsigned short u;
    __builtin_memcpy(&u, &h, 2);
    return u;
}

static __device__ __forceinline__ float fexp2(float x) {
#if __has_builtin(__builtin_amdgcn_exp2f)
    return __builtin_amdgcn_exp2f(x);     // v_exp_f32 directly
#else
    return __expf(x * 0.6931471805599453f);
#endif
}

// ---------------- Kernel 1: fused prep -----------------------------------------------
// blocks [0,8192):   E -> bf16 cast + g[n][v] = E[n][v,:] . dec_w[n*64:]
// blocks [8192,12288): Q = LayerNorm(enc(x) + PE) * QSCALE -> bf16, wave per row
__global__ void prep(const float* __restrict__ x, const float* __restrict__ emb,
                     const float* __restrict__ enc_w, const float* __restrict__ enc_b,
                     const float* __restrict__ ln_w, const float* __restrict__ ln_b,
                     const float* __restrict__ dec_w,
                     unsigned short* __restrict__ qbf, unsigned short* __restrict__ ebf,
                     float* __restrict__ g) {
    if (blockIdx.x < 8192) {
        int i4  = blockIdx.x * 256 + threadIdx.x;   // float4 index, total 2097152
        int row = i4 >> 4;                          // (n, v) row
        int c   = i4 & 15;
        int n   = row >> 14;
        f32x4 v = ((const f32x4*)emb)[i4];
        ushort4 u = make_ushort4(f2bf(v.x), f2bf(v.y), f2bf(v.z), f2bf(v.w));
        ((ushort4*)ebf)[i4] = u;
        const float* dw = dec_w + n * 64 + c * 4;
        float p = v.x * dw[0] + v.y * dw[1] + v.z * dw[2] + v.w * dw[3];
        p += __shfl_xor(p, 1); p += __shfl_xor(p, 2);
        p += __shfl_xor(p, 4); p += __shfl_xor(p, 8);
        if (c == 0) g[row] = p;
    } else {
        int row  = (blockIdx.x - 8192) * 4 + (threadIdx.x >> 6);  // n*2048 + q
        int h    = threadIdx.x & 63;
        int n = row >> 11;
        int q = row & 2047;
        int t = q & 511;
        float xv = x[q];
        int d = n * 64 + h;
        float h2  = (float)(h & ~1);
        float div = __expf(h2 * (-9.210340371976184f / 64.0f));
        float ang = (float)t * div;
        float pe  = (h & 1) ? __cosf(ang) : __sinf(ang);
        float v = xv * enc_w[d] + enc_b[d] + pe;
        float s = v;
        #pragma unroll
        for (int off = 1; off < 64; off <<= 1) s += __shfl_xor(s, off);
        float mu = s * (1.0f / 64.0f);
        float dd = v - mu;
        float s2 = dd * dd;
        #pragma unroll
        for (int off = 1; off < 64; off <<= 1) s2 += __shfl_xor(s2, off);
        float var = s2 * (1.0f / 64.0f);
        float y = dd * rsqrtf(var + 1e-5f) * ln_w[h] + ln_b[h];
        qbf[row * 64 + h] = f2bf(y * QSCALE);
    }
}

// ---------------- Kernel 2: attn — barrier-free, LDS-free ---------------------------
// grid 2048, block 256 (4 waves). blockIdx = qchunk(8)*256 + vslice(32)*8 + head(8)
// => blockIdx % 8 == head: each XCD's round-robin share touches ONE head's E (2MB < 4MB L2).
// Wave w handles q64-chunk (qchunk*4+w)*64 (Q persistent in VGPRs) over a 512-row
// vocab slice. Partial num/den merged via global float atomics.
__global__ void __launch_bounds__(256, 8)
attn(const unsigned short* __restrict__ qbf, const unsigned short* __restrict__ ebf,
     const float* __restrict__ g, float* __restrict__ part) {
    int tid  = threadIdx.x;
    int w    = tid >> 6;
    int lane = tid & 63;
    int quad = lane >> 4;
    int l15  = lane & 15;
    int hv     = blockIdx.x & 255;
    int head   = hv & 7;
    int vslice = hv >> 3;                 // 0..31, 512 rows each
    int qchunk = blockIdx.x >> 8;
    int qbase  = (qchunk * 4 + w) * 64;

    // persistent Q B-frags: B[k=hs][n=q], lane: n=l15, k = kf*32 + quad*8 + j
    const short* qp = (const short*)qbf + (size_t)(head * QPH + qbase) * HS;
    bf16x8 qf[4][2];
    #pragma unroll
    for (int qt = 0; qt < 4; ++qt) {
        const short* qrow = qp + (qt * 16 + l15) * HS + quad * 8;
        qf[qt][0] = *(const bf16x8*)(qrow);
        qf[qt][1] = *(const bf16x8*)(qrow + 32);
    }

    const short* ep = (const short*)ebf + ((size_t)head * VOCAB + vslice * 512) * HS;
    const float* gp = g + head * VOCAB + vslice * 512;

    float num[4] = {0.f, 0.f, 0.f, 0.f};
    float den[4] = {0.f, 0.f, 0.f, 0.f};
    const f32x4 z = {0.f, 0.f, 0.f, 0.f};

    for (int it = 0; it < 16; ++it) {
        int vb = it * 32;
        // A-frags direct from global (L2): A[m=v][k], lane: m=l15(+16), k=kf*32+quad*8+j
        const short* e0 = ep + (size_t)(vb + l15) * HS + quad * 8;
        const short* e1 = ep + (size_t)(vb + 16 + l15) * HS + quad * 8;
        bf16x8 a00 = *(const bf16x8*)(e0);
        bf16x8 a01 = *(const bf16x8*)(e0 + 32);
        bf16x8 a10 = *(const bf16x8*)(e1);
        bf16x8 a11 = *(const bf16x8*)(e1 + 32);
        f32x4 gv0 = *(const f32x4*)(gp + vb + quad * 4);
        f32x4 gv1 = *(const f32x4*)(gp + vb + 16 + quad * 4);
        #pragma unroll
        for (int qt = 0; qt < 4; ++qt) {
            f32x4 acc0 = __builtin_amdgcn_mfma_f32_16x16x32_bf16(a00, qf[qt][0], z, 0, 0, 0);
            acc0       = __builtin_amdgcn_mfma_f32_16x16x32_bf16(a01, qf[qt][1], acc0, 0, 0, 0);
            f32x4 acc1 = __builtin_amdgcn_mfma_f32_16x16x32_bf16(a10, qf[qt][0], z, 0, 0, 0);
            acc1       = __builtin_amdgcn_mfma_f32_16x16x32_bf16(a11, qf[qt][1], acc1, 0, 0, 0);
            // D layout: col=l15=q, row=quad*4+r = v-within-16-tile
            #pragma unroll
            for (int r = 0; r < 4; ++r) {
                float p0 = fexp2(acc0[r]);
                float p1 = fexp2(acc1[r]);
                den[qt] += p0 + p1;
                num[qt] += p0 * gv0[r] + p1 * gv1[r];
            }
        }
    }

    // reduce across quads (same l15 = same q)
    #pragma unroll
    for (int qt = 0; qt < 4; ++qt) {
        num[qt] += __shfl_xor(num[qt], 16); num[qt] += __shfl_xor(num[qt], 32);
        den[qt] += __shfl_xor(den[qt], 16); den[qt] += __shfl_xor(den[qt], 32);
    }
    // quad i commits q-tile i: one num + one den atomic per lane
    int qg = qbase + quad * 16 + l15;
    float nv = num[quad];
    float dv = den[quad];
    float* pp = part + (size_t)(head * QPH + qg) * 2;
    atomicAdd(pp,     nv);
    atomicAdd(pp + 1, dv);
}

// ---------------- Kernel 3: out[q] = dec_b + sum_n num/den ---------------------------
__global__ void fin(const float* __restrict__ part, const float* __restrict__ dec_b,
                    float* __restrict__ out) {
    int q = blockIdx.x * 256 + threadIdx.x;   // 0..2047
    float s = dec_b[0];
    #pragma unroll
    for (int n = 0; n < NH; ++n) {
        float nv = part[(size_t)(n * QPH + q) * 2];
        float dv = part[(size_t)(n * QPH + q) * 2 + 1];
        s += nv / dv;
    }
    out[q] = s;
}

extern "C" void kernel_launch(void* const* d_in, const int* in_sizes, int n_in,
                              void* d_out, int out_size, void* d_ws, size_t ws_size,
                              hipStream_t stream) {
    const float* x     = (const float*)d_in[0];
    const float* emb   = (const float*)d_in[1];
    const float* enc_w = (const float*)d_in[2];
    const float* enc_b = (const float*)d_in[3];
    const float* ln_w  = (const float*)d_in[4];
    const float* ln_b  = (const float*)d_in[5];
    const float* dec_w = (const float*)d_in[6];
    const float* dec_b = (const float*)d_in[7];
    float* out = (float*)d_out;

    char* ws = (char*)d_ws;
    unsigned short* qbf  = (unsigned short*)(ws);                        // 2 MB
    unsigned short* ebf  = (unsigned short*)(ws + 2097152);              // 16 MB
    float*          g    = (float*)(ws + 2097152 + 16777216);            // 512 KB
    float*          part = (float*)(ws + 2097152 + 16777216 + 524288);   // 128 KB
    size_t part_bytes = (size_t)NH * QPH * 2 * sizeof(float);

    hipMemsetAsync(part, 0, part_bytes, stream);   // ws is re-poisoned before every launch
    hipLaunchKernelGGL(prep, dim3(12288), dim3(256), 0, stream,
                       x, emb, enc_w, enc_b, ln_w, ln_b, dec_w, qbf, ebf, g);
    hipLaunchKernelGGL(attn, dim3(2048), dim3(256), 0, stream, qbf, ebf, g, part);
    hipLaunchKernelGGL(fin,  dim3(8),    dim3(256), 0, stream, part, dec_b, out);
}

// Round 5
// 291.786 us; speedup vs baseline: 2.9873x; 2.9873x over previous
//
#include <hip/hip_runtime.h>
#include <hip/hip_bf16.h>
#include <math.h>

#define NH 8
#define HS 64
#define VOCAB 16384
#define QPH 2048                         // queries per head = b(4) * t(512)
// fold 1/sqrt(512) * log2(e) into Q so the epilogue is p = exp2(score)
#define QSCALE (0.04419417382415922f * 1.4426950408889634f)

typedef __attribute__((ext_vector_type(8))) short bf16x8;
typedef __attribute__((ext_vector_type(4))) float f32x4;

static __device__ __forceinline__ unsigned short f2bf(float f) {
    __hip_bfloat16 h = __float2bfloat16(f);
    unsigned short u;
    __builtin_memcpy(&u, &h, 2);
    return u;
}

static __device__ __forceinline__ float fexp2(float x) {
#if __has_builtin(__builtin_amdgcn_exp2f)
    return __builtin_amdgcn_exp2f(x);     // v_exp_f32 directly
#else
    return __expf(x * 0.6931471805599453f);
#endif
}

// ---------------- Kernel 1: fused prep -----------------------------------------------
// blocks [0,8192):   E -> bf16 cast + g[n][v] = E[n][v,:] . dec_w[n*64:]
// blocks [8192,12288): Q = LayerNorm(enc(x) + PE) * QSCALE -> bf16, wave per row
__global__ void prep(const float* __restrict__ x, const float* __restrict__ emb,
                     const float* __restrict__ enc_w, const float* __restrict__ enc_b,
                     const float* __restrict__ ln_w, const float* __restrict__ ln_b,
                     const float* __restrict__ dec_w,
                     unsigned short* __restrict__ qbf, unsigned short* __restrict__ ebf,
                     float* __restrict__ g) {
    if (blockIdx.x < 8192) {
        int i4  = blockIdx.x * 256 + threadIdx.x;   // float4 index, total 2097152
        int row = i4 >> 4;                          // (n, v) row
        int c   = i4 & 15;
        int n   = row >> 14;
        f32x4 v = ((const f32x4*)emb)[i4];
        ushort4 u = make_ushort4(f2bf(v.x), f2bf(v.y), f2bf(v.z), f2bf(v.w));
        ((ushort4*)ebf)[i4] = u;
        const float* dw = dec_w + n * 64 + c * 4;
        float p = v.x * dw[0] + v.y * dw[1] + v.z * dw[2] + v.w * dw[3];
        p += __shfl_xor(p, 1); p += __shfl_xor(p, 2);
        p += __shfl_xor(p, 4); p += __shfl_xor(p, 8);
        if (c == 0) g[row] = p;
    } else {
        int row  = (blockIdx.x - 8192) * 4 + (threadIdx.x >> 6);  // n*2048 + q
        int h    = threadIdx.x & 63;
        int n = row >> 11;
        int q = row & 2047;
        int t = q & 511;
        float xv = x[q];
        int d = n * 64 + h;
        float h2  = (float)(h & ~1);
        float div = __expf(h2 * (-9.210340371976184f / 64.0f));
        float ang = (float)t * div;
        float pe  = (h & 1) ? __cosf(ang) : __sinf(ang);
        float v = xv * enc_w[d] + enc_b[d] + pe;
        float s = v;
        #pragma unroll
        for (int off = 1; off < 64; off <<= 1) s += __shfl_xor(s, off);
        float mu = s * (1.0f / 64.0f);
        float dd = v - mu;
        float s2 = dd * dd;
        #pragma unroll
        for (int off = 1; off < 64; off <<= 1) s2 += __shfl_xor(s2, off);
        float var = s2 * (1.0f / 64.0f);
        float y = dd * rsqrtf(var + 1e-5f) * ln_w[h] + ln_b[h];
        qbf[row * 64 + h] = f2bf(y * QSCALE);
    }
}

// ---------------- Kernel 2: attn — barrier-free, LDS-free ---------------------------
// grid 2048, block 256 (4 waves). blockIdx = qchunk(8)*256 + vslice(32)*8 + head(8)
// => blockIdx % 8 == head: each XCD's round-robin share touches ONE head's E (2MB < 4MB L2).
// Wave w handles q64-chunk (qchunk*4+w)*64 (Q persistent in VGPRs) over a 512-row
// vocab slice. Partial num/den merged via global float atomics.
// NOTE: __launch_bounds__(256,4), NOT (256,8): the ,8 hint capped the allocator at
// 32 VGPRs and spilled the Q fragments to scratch (R4: WRITE_SIZE 4MB->1.5GB,
// 82us->770us). 52 VGPRs already permits 8 waves/SIMD (capacity halves at 64).
__global__ void __launch_bounds__(256, 4)
attn(const unsigned short* __restrict__ qbf, const unsigned short* __restrict__ ebf,
     const float* __restrict__ g, float* __restrict__ part) {
    int tid  = threadIdx.x;
    int w    = tid >> 6;
    int lane = tid & 63;
    int quad = lane >> 4;
    int l15  = lane & 15;
    int hv     = blockIdx.x & 255;
    int head   = hv & 7;
    int vslice = hv >> 3;                 // 0..31, 512 rows each
    int qchunk = blockIdx.x >> 8;
    int qbase  = (qchunk * 4 + w) * 64;

    // persistent Q B-frags: B[k=hs][n=q], lane: n=l15, k = kf*32 + quad*8 + j
    const short* qp = (const short*)qbf + (size_t)(head * QPH + qbase) * HS;
    bf16x8 qf[4][2];
    #pragma unroll
    for (int qt = 0; qt < 4; ++qt) {
        const short* qrow = qp + (qt * 16 + l15) * HS + quad * 8;
        qf[qt][0] = *(const bf16x8*)(qrow);
        qf[qt][1] = *(const bf16x8*)(qrow + 32);
    }

    const short* ep = (const short*)ebf + ((size_t)head * VOCAB + vslice * 512) * HS;
    const float* gp = g + head * VOCAB + vslice * 512;

    float num[4] = {0.f, 0.f, 0.f, 0.f};
    float den[4] = {0.f, 0.f, 0.f, 0.f};
    const f32x4 z = {0.f, 0.f, 0.f, 0.f};

    for (int it = 0; it < 16; ++it) {
        int vb = it * 32;
        // A-frags direct from global (L2): A[m=v][k], lane: m=l15(+16), k=kf*32+quad*8+j
        const short* e0 = ep + (size_t)(vb + l15) * HS + quad * 8;
        const short* e1 = ep + (size_t)(vb + 16 + l15) * HS + quad * 8;
        bf16x8 a00 = *(const bf16x8*)(e0);
        bf16x8 a01 = *(const bf16x8*)(e0 + 32);
        bf16x8 a10 = *(const bf16x8*)(e1);
        bf16x8 a11 = *(const bf16x8*)(e1 + 32);
        f32x4 gv0 = *(const f32x4*)(gp + vb + quad * 4);
        f32x4 gv1 = *(const f32x4*)(gp + vb + 16 + quad * 4);
        #pragma unroll
        for (int qt = 0; qt < 4; ++qt) {
            f32x4 acc0 = __builtin_amdgcn_mfma_f32_16x16x32_bf16(a00, qf[qt][0], z, 0, 0, 0);
            acc0       = __builtin_amdgcn_mfma_f32_16x16x32_bf16(a01, qf[qt][1], acc0, 0, 0, 0);
            f32x4 acc1 = __builtin_amdgcn_mfma_f32_16x16x32_bf16(a10, qf[qt][0], z, 0, 0, 0);
            acc1       = __builtin_amdgcn_mfma_f32_16x16x32_bf16(a11, qf[qt][1], acc1, 0, 0, 0);
            // D layout: col=l15=q, row=quad*4+r = v-within-16-tile
            #pragma unroll
            for (int r = 0; r < 4; ++r) {
                float p0 = fexp2(acc0[r]);
                float p1 = fexp2(acc1[r]);
                den[qt] += p0 + p1;
                num[qt] += p0 * gv0[r] + p1 * gv1[r];
            }
        }
    }

    // reduce across quads (same l15 = same q)
    #pragma unroll
    for (int qt = 0; qt < 4; ++qt) {
        num[qt] += __shfl_xor(num[qt], 16); num[qt] += __shfl_xor(num[qt], 32);
        den[qt] += __shfl_xor(den[qt], 16); den[qt] += __shfl_xor(den[qt], 32);
    }
    // quad i commits q-tile i: one num + one den atomic per lane
    int qg = qbase + quad * 16 + l15;
    float nv = num[quad];
    float dv = den[quad];
    float* pp = part + (size_t)(head * QPH + qg) * 2;
    atomicAdd(pp,     nv);
    atomicAdd(pp + 1, dv);
}

// ---------------- Kernel 3: out[q] = dec_b + sum_n num/den ---------------------------
__global__ void fin(const float* __restrict__ part, const float* __restrict__ dec_b,
                    float* __restrict__ out) {
    int q = blockIdx.x * 256 + threadIdx.x;   // 0..2047
    float s = dec_b[0];
    #pragma unroll
    for (int n = 0; n < NH; ++n) {
        float nv = part[(size_t)(n * QPH + q) * 2];
        float dv = part[(size_t)(n * QPH + q) * 2 + 1];
        s += nv / dv;
    }
    out[q] = s;
}

extern "C" void kernel_launch(void* const* d_in, const int* in_sizes, int n_in,
                              void* d_out, int out_size, void* d_ws, size_t ws_size,
                              hipStream_t stream) {
    const float* x     = (const float*)d_in[0];
    const float* emb   = (const float*)d_in[1];
    const float* enc_w = (const float*)d_in[2];
    const float* enc_b = (const float*)d_in[3];
    const float* ln_w  = (const float*)d_in[4];
    const float* ln_b  = (const float*)d_in[5];
    const float* dec_w = (const float*)d_in[6];
    const float* dec_b = (const float*)d_in[7];
    float* out = (float*)d_out;

    char* ws = (char*)d_ws;
    unsigned short* qbf  = (unsigned short*)(ws);                        // 2 MB
    unsigned short* ebf  = (unsigned short*)(ws + 2097152);              // 16 MB
    float*          g    = (float*)(ws + 2097152 + 16777216);            // 512 KB
    float*          part = (float*)(ws + 2097152 + 16777216 + 524288);   // 128 KB
    size_t part_bytes = (size_t)NH * QPH * 2 * sizeof(float);

    hipMemsetAsync(part, 0, part_bytes, stream);   // ws is re-poisoned before every launch
    hipLaunchKernelGGL(prep, dim3(12288), dim3(256), 0, stream,
                       x, emb, enc_w, enc_b, ln_w, ln_b, dec_w, qbf, ebf, g);
    hipLaunchKernelGGL(attn, dim3(2048), dim3(256), 0, stream, qbf, ebf, g, part);
    hipLaunchKernelGGL(fin,  dim3(8),    dim3(256), 0, stream, part, dec_b, out);
}

// Round 6
// 232.423 us; speedup vs baseline: 3.7502x; 1.2554x over previous
//
#include <hip/hip_runtime.h>
#include <hip/hip_bf16.h>
#include <math.h>

#define NH 8
#define HS 64
#define VOCAB 16384
#define QPH 2048                         // queries per head = b(4) * t(512)
// fold 1/sqrt(512) * log2(e) into Q so the epilogue is p = exp2(score)
#define QSCALE (0.04419417382415922f * 1.4426950408889634f)

typedef __attribute__((ext_vector_type(8))) short bf16x8;
typedef __attribute__((ext_vector_type(4))) float f32x4;

static __device__ __forceinline__ unsigned short f2bf(float f) {
    __hip_bfloat16 h = __float2bfloat16(f);
    unsigned short u;
    __builtin_memcpy(&u, &h, 2);
    return u;
}

static __device__ __forceinline__ float fexp2(float x) {
#if __has_builtin(__builtin_amdgcn_exp2f)
    return __builtin_amdgcn_exp2f(x);     // v_exp_f32 directly
#else
    return __expf(x * 0.6931471805599453f);
#endif
}

// ---------------- Kernel 1: fused prep -----------------------------------------------
// blocks [0,8192):   E -> bf16 cast + g[n][v] = E[n][v,:] . dec_w[n*64:]
// blocks [8192,12288): Q = LayerNorm(enc(x) + PE) * QSCALE -> bf16, wave per row
__global__ void prep(const float* __restrict__ x, const float* __restrict__ emb,
                     const float* __restrict__ enc_w, const float* __restrict__ enc_b,
                     const float* __restrict__ ln_w, const float* __restrict__ ln_b,
                     const float* __restrict__ dec_w,
                     unsigned short* __restrict__ qbf, unsigned short* __restrict__ ebf,
                     float* __restrict__ g) {
    if (blockIdx.x < 8192) {
        int i4  = blockIdx.x * 256 + threadIdx.x;   // float4 index, total 2097152
        int row = i4 >> 4;                          // (n, v) row
        int c   = i4 & 15;
        int n   = row >> 14;
        f32x4 v = ((const f32x4*)emb)[i4];
        ushort4 u = make_ushort4(f2bf(v.x), f2bf(v.y), f2bf(v.z), f2bf(v.w));
        ((ushort4*)ebf)[i4] = u;
        const float* dw = dec_w + n * 64 + c * 4;
        float p = v.x * dw[0] + v.y * dw[1] + v.z * dw[2] + v.w * dw[3];
        p += __shfl_xor(p, 1); p += __shfl_xor(p, 2);
        p += __shfl_xor(p, 4); p += __shfl_xor(p, 8);
        if (c == 0) g[row] = p;
    } else {
        int row  = (blockIdx.x - 8192) * 4 + (threadIdx.x >> 6);  // n*2048 + q
        int h    = threadIdx.x & 63;
        int n = row >> 11;
        int q = row & 2047;
        int t = q & 511;
        float xv = x[q];
        int d = n * 64 + h;
        float h2  = (float)(h & ~1);
        float div = __expf(h2 * (-9.210340371976184f / 64.0f));
        float ang = (float)t * div;
        float pe  = (h & 1) ? __cosf(ang) : __sinf(ang);
        float v = xv * enc_w[d] + enc_b[d] + pe;
        float s = v;
        #pragma unroll
        for (int off = 1; off < 64; off <<= 1) s += __shfl_xor(s, off);
        float mu = s * (1.0f / 64.0f);
        float dd = v - mu;
        float s2 = dd * dd;
        #pragma unroll
        for (int off = 1; off < 64; off <<= 1) s2 += __shfl_xor(s2, off);
        float var = s2 * (1.0f / 64.0f);
        float y = dd * rsqrtf(var + 1e-5f) * ln_w[h] + ln_b[h];
        qbf[row * 64 + h] = f2bf(y * QSCALE);
    }
}

// ---------------- Kernel 2: attn — barrier-free, LDS-free ---------------------------
// grid 2048 = qchunk(16) * 128 + vslice(16)*8 + head(8); block 256 (4 waves).
// blockIdx % 8 == head: each XCD's share touches ONE head's E (2MB < 4MB L2).
// Wave w handles 32 q (2 MFMA q-tiles, Q persistent in 16 VGPRs) over a 1024-row
// vocab slice => trip-32 K-loop. Partials merged via global float atomics.
// CODEGEN NOTES (hard-won):
//  - __launch_bounds__(256,4) and NOT (,8): the ,8 hint forced 32 VGPRs and
//    spilled Q frags to scratch (R4: WRITE 4MB->1.5GB, 770us).
//  - K-loop trip count must stay 32: at trip 16 LLVM fully unrolls, hoists
//    loads, blows past the register budget and spills in-loop
//    (R5: FETCH 9.5->384MB, WRITE 4->455MB, 204us).
//  - 2 q-tiles/wave (not 4) so VGPR <= 64 => 8 waves/SIMD possible with
//    8 blocks/CU (grid 2048).
__global__ void __launch_bounds__(256, 4)
attn(const unsigned short* __restrict__ qbf, const unsigned short* __restrict__ ebf,
     const float* __restrict__ g, float* __restrict__ part) {
    int tid  = threadIdx.x;
    int w    = tid >> 6;
    int lane = tid & 63;
    int quad = lane >> 4;
    int l15  = lane & 15;
    int head   = blockIdx.x & 7;
    int vslice = (blockIdx.x >> 3) & 15;   // 16 slices x 1024 rows
    int qchunk = blockIdx.x >> 7;          // 16 chunks x 128 q
    int qbase  = (qchunk * 4 + w) * 32;    // 32 q per wave

    // persistent Q B-frags: B[k=hs][n=q], lane: n=l15, k = kf*32 + quad*8 + j
    const short* qp = (const short*)qbf + (size_t)(head * QPH + qbase) * HS;
    bf16x8 qf[2][2];
    #pragma unroll
    for (int qt = 0; qt < 2; ++qt) {
        const short* qrow = qp + (qt * 16 + l15) * HS + quad * 8;
        qf[qt][0] = *(const bf16x8*)(qrow);
        qf[qt][1] = *(const bf16x8*)(qrow + 32);
    }

    const short* ep = (const short*)ebf + ((size_t)head * VOCAB + vslice * 1024) * HS;
    const float* gp = g + head * VOCAB + vslice * 1024;

    float num[2] = {0.f, 0.f};
    float den[2] = {0.f, 0.f};
    const f32x4 z = {0.f, 0.f, 0.f, 0.f};

    for (int it = 0; it < 32; ++it) {
        int vb = it * 32;
        // A-frags direct from global (L2): A[m=v][k], lane: m=l15(+16), k=kf*32+quad*8+j
        const short* e0 = ep + (size_t)(vb + l15) * HS + quad * 8;
        const short* e1 = ep + (size_t)(vb + 16 + l15) * HS + quad * 8;
        bf16x8 a00 = *(const bf16x8*)(e0);
        bf16x8 a01 = *(const bf16x8*)(e0 + 32);
        bf16x8 a10 = *(const bf16x8*)(e1);
        bf16x8 a11 = *(const bf16x8*)(e1 + 32);
        f32x4 gv0 = *(const f32x4*)(gp + vb + quad * 4);
        f32x4 gv1 = *(const f32x4*)(gp + vb + 16 + quad * 4);
        #pragma unroll
        for (int qt = 0; qt < 2; ++qt) {
            f32x4 acc0 = __builtin_amdgcn_mfma_f32_16x16x32_bf16(a00, qf[qt][0], z, 0, 0, 0);
            acc0       = __builtin_amdgcn_mfma_f32_16x16x32_bf16(a01, qf[qt][1], acc0, 0, 0, 0);
            f32x4 acc1 = __builtin_amdgcn_mfma_f32_16x16x32_bf16(a10, qf[qt][0], z, 0, 0, 0);
            acc1       = __builtin_amdgcn_mfma_f32_16x16x32_bf16(a11, qf[qt][1], acc1, 0, 0, 0);
            // D layout: col=l15=q, row=quad*4+r = v-within-16-tile
            #pragma unroll
            for (int r = 0; r < 4; ++r) {
                float p0 = fexp2(acc0[r]);
                float p1 = fexp2(acc1[r]);
                den[qt] += p0 + p1;
                num[qt] += p0 * gv0[r] + p1 * gv1[r];
            }
        }
    }

    // reduce across quads (same l15 = same q)
    #pragma unroll
    for (int qt = 0; qt < 2; ++qt) {
        num[qt] += __shfl_xor(num[qt], 16); num[qt] += __shfl_xor(num[qt], 32);
        den[qt] += __shfl_xor(den[qt], 16); den[qt] += __shfl_xor(den[qt], 32);
    }
    // quads 0 and 2 commit tiles 0 and 1: one num + one den atomic per lane
    if (!(quad & 1)) {
        int qt = quad >> 1;
        int qg = qbase + qt * 16 + l15;
        float* pp = part + (size_t)(head * QPH + qg) * 2;
        atomicAdd(pp,     num[qt]);
        atomicAdd(pp + 1, den[qt]);
    }
}

// ---------------- Kernel 3: out[q] = dec_b + sum_n num/den ---------------------------
__global__ void fin(const float* __restrict__ part, const float* __restrict__ dec_b,
                    float* __restrict__ out) {
    int q = blockIdx.x * 256 + threadIdx.x;   // 0..2047
    float s = dec_b[0];
    #pragma unroll
    for (int n = 0; n < NH; ++n) {
        float nv = part[(size_t)(n * QPH + q) * 2];
        float dv = part[(size_t)(n * QPH + q) * 2 + 1];
        s += nv / dv;
    }
    out[q] = s;
}

extern "C" void kernel_launch(void* const* d_in, const int* in_sizes, int n_in,
                              void* d_out, int out_size, void* d_ws, size_t ws_size,
                              hipStream_t stream) {
    const float* x     = (const float*)d_in[0];
    const float* emb   = (const float*)d_in[1];
    const float* enc_w = (const float*)d_in[2];
    const float* enc_b = (const float*)d_in[3];
    const float* ln_w  = (const float*)d_in[4];
    const float* ln_b  = (const float*)d_in[5];
    const float* dec_w = (const float*)d_in[6];
    const float* dec_b = (const float*)d_in[7];
    float* out = (float*)d_out;

    char* ws = (char*)d_ws;
    unsigned short* qbf  = (unsigned short*)(ws);                        // 2 MB
    unsigned short* ebf  = (unsigned short*)(ws + 2097152);              // 16 MB
    float*          g    = (float*)(ws + 2097152 + 16777216);            // 512 KB
    float*          part = (float*)(ws + 2097152 + 16777216 + 524288);   // 128 KB
    size_t part_bytes = (size_t)NH * QPH * 2 * sizeof(float);

    hipMemsetAsync(part, 0, part_bytes, stream);   // ws is re-poisoned before every launch
    hipLaunchKernelGGL(prep, dim3(12288), dim3(256), 0, stream,
                       x, emb, enc_w, enc_b, ln_w, ln_b, dec_w, qbf, ebf, g);
    hipLaunchKernelGGL(attn, dim3(2048), dim3(256), 0, stream, qbf, ebf, g, part);
    hipLaunchKernelGGL(fin,  dim3(8),    dim3(256), 0, stream, part, dec_b, out);
}

// Round 7
// 170.205 us; speedup vs baseline: 5.1211x; 1.3656x over previous
//
#include <hip/hip_runtime.h>
#include <hip/hip_bf16.h>
#include <math.h>

#define NH 8
#define HS 64
#define VOCAB 16384
#define QPH 2048                         // queries per head = b(4) * t(512)
// fold 1/sqrt(512) * log2(e) into Q so the epilogue is p = exp2(score)
#define QSCALE (0.04419417382415922f * 1.4426950408889634f)

typedef __attribute__((ext_vector_type(8))) short bf16x8;
typedef __attribute__((ext_vector_type(4))) float f32x4;

static __device__ __forceinline__ unsigned short f2bf(float f) {
    __hip_bfloat16 h = __float2bfloat16(f);
    unsigned short u;
    __builtin_memcpy(&u, &h, 2);
    return u;
}

static __device__ __forceinline__ float fexp2(float x) {
#if __has_builtin(__builtin_amdgcn_exp2f)
    return __builtin_amdgcn_exp2f(x);     // v_exp_f32 directly
#else
    return __expf(x * 0.6931471805599453f);
#endif
}

// ---------------- Kernel 1: fused prep -----------------------------------------------
// blocks [0,8192):   E -> bf16 cast + g[n][v] = E[n][v,:] . dec_w[n*64:]
// blocks [8192,12288): Q = LayerNorm(enc(x) + PE) * QSCALE -> bf16, wave per row
__global__ void prep(const float* __restrict__ x, const float* __restrict__ emb,
                     const float* __restrict__ enc_w, const float* __restrict__ enc_b,
                     const float* __restrict__ ln_w, const float* __restrict__ ln_b,
                     const float* __restrict__ dec_w,
                     unsigned short* __restrict__ qbf, unsigned short* __restrict__ ebf,
                     float* __restrict__ g) {
    if (blockIdx.x < 8192) {
        int i4  = blockIdx.x * 256 + threadIdx.x;   // float4 index, total 2097152
        int row = i4 >> 4;                          // (n, v) row
        int c   = i4 & 15;
        int n   = row >> 14;
        f32x4 v = ((const f32x4*)emb)[i4];
        ushort4 u = make_ushort4(f2bf(v.x), f2bf(v.y), f2bf(v.z), f2bf(v.w));
        ((ushort4*)ebf)[i4] = u;
        const float* dw = dec_w + n * 64 + c * 4;
        float p = v.x * dw[0] + v.y * dw[1] + v.z * dw[2] + v.w * dw[3];
        p += __shfl_xor(p, 1); p += __shfl_xor(p, 2);
        p += __shfl_xor(p, 4); p += __shfl_xor(p, 8);
        if (c == 0) g[row] = p;
    } else {
        int row  = (blockIdx.x - 8192) * 4 + (threadIdx.x >> 6);  // n*2048 + q
        int h    = threadIdx.x & 63;
        int n = row >> 11;
        int q = row & 2047;
        int t = q & 511;
        float xv = x[q];
        int d = n * 64 + h;
        float h2  = (float)(h & ~1);
        float div = __expf(h2 * (-9.210340371976184f / 64.0f));
        float ang = (float)t * div;
        float pe  = (h & 1) ? __cosf(ang) : __sinf(ang);
        float v = xv * enc_w[d] + enc_b[d] + pe;
        float s = v;
        #pragma unroll
        for (int off = 1; off < 64; off <<= 1) s += __shfl_xor(s, off);
        float mu = s * (1.0f / 64.0f);
        float dd = v - mu;
        float s2 = dd * dd;
        #pragma unroll
        for (int off = 1; off < 64; off <<= 1) s2 += __shfl_xor(s2, off);
        float var = s2 * (1.0f / 64.0f);
        float y = dd * rsqrtf(var + 1e-5f) * ln_w[h] + ln_b[h];
        qbf[row * 64 + h] = f2bf(y * QSCALE);
    }
}

// ---------------- Kernel 2: attn — R3 shape + 1-deep register software pipeline ------
// grid 1024 = qchunk(8)*128 + vslice(16)*8 + head(8); block 256 (4 waves).
// blockIdx % 8 == head: each XCD's share touches ONE head's E (2MB < 4MB L2).
// Wave w: 64 q (4 q-tiles, Q persistent 32 VGPR) x 1024-row vocab slice, trip-32.
// Prefetches it+1's E-frags + g while computing it (2x VMEM in flight/wave).
// CODEGEN NOTES (hard-won):
//  - __launch_bounds__(256,4) NOT (,8): the ,8 hint forced 32 VGPRs -> Q frags
//    spilled to scratch (R4: WRITE 4MB->1.5GB, 770us).
//  - K-loop trip must stay 32: at trip 16 LLVM fully unrolls, hoists loads,
//    spills in-loop (R5: FETCH 384MB WRITE 455MB, 204us).
//  - q/wave must stay 64: halving to 32 doubled E traffic, 143us (R6) —
//    kernel is VMEM-latency bound, E-reuse per load is the currency.
//  - at grid 1024 (4 blk/CU) anything <=128 VGPR is occupancy-free.
__global__ void __launch_bounds__(256, 4)
attn(const unsigned short* __restrict__ qbf, const unsigned short* __restrict__ ebf,
     const float* __restrict__ g, float2* __restrict__ part) {
    int tid  = threadIdx.x;
    int w    = tid >> 6;
    int lane = tid & 63;
    int quad = lane >> 4;
    int l15  = lane & 15;
    int head   = blockIdx.x & 7;
    int vslice = (blockIdx.x >> 3) & 15;   // 16 slices x 1024 rows
    int qchunk = blockIdx.x >> 7;          // 8 chunks x 256 q
    int qbase  = (qchunk * 4 + w) * 64;    // 64 q per wave

    // persistent Q B-frags: B[k=hs][n=q], lane: n=l15, k = kf*32 + quad*8 + j
    const short* qp = (const short*)qbf + (size_t)(head * QPH + qbase) * HS;
    bf16x8 qf[4][2];
    #pragma unroll
    for (int qt = 0; qt < 4; ++qt) {
        const short* qrow = qp + (qt * 16 + l15) * HS + quad * 8;
        qf[qt][0] = *(const bf16x8*)(qrow);
        qf[qt][1] = *(const bf16x8*)(qrow + 32);
    }

    const short* ep = (const short*)ebf + ((size_t)head * VOCAB + vslice * 1024) * HS;
    const float* gp = g + head * VOCAB + vslice * 1024;

    float num[4] = {0.f, 0.f, 0.f, 0.f};
    float den[4] = {0.f, 0.f, 0.f, 0.f};
    const f32x4 z = {0.f, 0.f, 0.f, 0.f};

    // prologue: load iteration 0's fragments
    const short* e0 = ep + (size_t)l15 * HS + quad * 8;
    const short* e1 = ep + (size_t)(16 + l15) * HS + quad * 8;
    bf16x8 a00 = *(const bf16x8*)(e0);
    bf16x8 a01 = *(const bf16x8*)(e0 + 32);
    bf16x8 a10 = *(const bf16x8*)(e1);
    bf16x8 a11 = *(const bf16x8*)(e1 + 32);
    f32x4 gv0 = *(const f32x4*)(gp + quad * 4);
    f32x4 gv1 = *(const f32x4*)(gp + 16 + quad * 4);

    for (int it = 0; it < 32; ++it) {
        // issue next iteration's loads (wrap on last iter; values unused)
        int vb2 = ((it + 1) & 31) * 32;
        const short* n0 = ep + (size_t)(vb2 + l15) * HS + quad * 8;
        const short* n1 = ep + (size_t)(vb2 + 16 + l15) * HS + quad * 8;
        bf16x8 b00 = *(const bf16x8*)(n0);
        bf16x8 b01 = *(const bf16x8*)(n0 + 32);
        bf16x8 b10 = *(const bf16x8*)(n1);
        bf16x8 b11 = *(const bf16x8*)(n1 + 32);
        f32x4 ngv0 = *(const f32x4*)(gp + vb2 + quad * 4);
        f32x4 ngv1 = *(const f32x4*)(gp + vb2 + 16 + quad * 4);

        #pragma unroll
        for (int qt = 0; qt < 4; ++qt) {
            f32x4 acc0 = __builtin_amdgcn_mfma_f32_16x16x32_bf16(a00, qf[qt][0], z, 0, 0, 0);
            acc0       = __builtin_amdgcn_mfma_f32_16x16x32_bf16(a01, qf[qt][1], acc0, 0, 0, 0);
            f32x4 acc1 = __builtin_amdgcn_mfma_f32_16x16x32_bf16(a10, qf[qt][0], z, 0, 0, 0);
            acc1       = __builtin_amdgcn_mfma_f32_16x16x32_bf16(a11, qf[qt][1], acc1, 0, 0, 0);
            // D layout: col=l15=q, row=quad*4+r = v-within-16-tile
            #pragma unroll
            for (int r = 0; r < 4; ++r) {
                float p0 = fexp2(acc0[r]);
                float p1 = fexp2(acc1[r]);
                den[qt] += p0 + p1;
                num[qt] += p0 * gv0[r] + p1 * gv1[r];
            }
        }
        // rotate pipeline registers
        a00 = b00; a01 = b01; a10 = b10; a11 = b11;
        gv0 = ngv0; gv1 = ngv1;
    }

    // reduce across quads (same l15 = same q)
    #pragma unroll
    for (int qt = 0; qt < 4; ++qt) {
        num[qt] += __shfl_xor(num[qt], 16); num[qt] += __shfl_xor(num[qt], 32);
        den[qt] += __shfl_xor(den[qt], 16); den[qt] += __shfl_xor(den[qt], 32);
    }
    // slotted partials (no atomics, no memset): part[vslice][head][q]
    // quad i commits q-tile i: 16 lanes store one float2 each
    int qg = qbase + quad * 16 + l15;
    part[((size_t)vslice * NH + head) * QPH + qg] = make_float2(num[quad], den[quad]);
}

// ---------------- Kernel 3: out[q] = dec_b + sum_n (sum_s num)/(sum_s den) -----------
__global__ void fin(const float2* __restrict__ part, const float* __restrict__ dec_b,
                    float* __restrict__ out) {
    int q = blockIdx.x * 256 + threadIdx.x;   // 0..2047
    float s = dec_b[0];
    #pragma unroll
    for (int n = 0; n < NH; ++n) {
        float nv = 0.f, dv = 0.f;
        #pragma unroll
        for (int sl = 0; sl < 16; ++sl) {
            float2 nd = part[((size_t)sl * NH + n) * QPH + q];
            nv += nd.x; dv += nd.y;
        }
        s += nv / dv;
    }
    out[q] = s;
}

extern "C" void kernel_launch(void* const* d_in, const int* in_sizes, int n_in,
                              void* d_out, int out_size, void* d_ws, size_t ws_size,
                              hipStream_t stream) {
    const float* x     = (const float*)d_in[0];
    const float* emb   = (const float*)d_in[1];
    const float* enc_w = (const float*)d_in[2];
    const float* enc_b = (const float*)d_in[3];
    const float* ln_w  = (const float*)d_in[4];
    const float* ln_b  = (const float*)d_in[5];
    const float* dec_w = (const float*)d_in[6];
    const float* dec_b = (const float*)d_in[7];
    float* out = (float*)d_out;

    char* ws = (char*)d_ws;
    unsigned short* qbf  = (unsigned short*)(ws);                        // 2 MB
    unsigned short* ebf  = (unsigned short*)(ws + 2097152);              // 16 MB
    float*          g    = (float*)(ws + 2097152 + 16777216);            // 512 KB
    float2*         part = (float2*)(ws + 2097152 + 16777216 + 524288);  // 2 MB (16*8*2048 float2)

    hipLaunchKernelGGL(prep, dim3(12288), dim3(256), 0, stream,
                       x, emb, enc_w, enc_b, ln_w, ln_b, dec_w, qbf, ebf, g);
    hipLaunchKernelGGL(attn, dim3(1024), dim3(256), 0, stream, qbf, ebf, g, part);
    hipLaunchKernelGGL(fin,  dim3(8),    dim3(256), 0, stream, part, dec_b, out);
}